// Round 4
// baseline (205.715 us; speedup 1.0000x reference)
//
#include <hip/hip_runtime.h>
#include <math.h>

#define IMG 512
#define TS 32                     // output tile 32x32
#define NT 16                     // tiles per side
#define NIMG 48                   // 16*3
#define NBLOCKS (NT * NT * NIMG)  // 12288
#define NPIX (16LL * 3 * 512 * 512)

#define C1F 0.0001f
#define C2F 0.0009f

// LDS row stride in bf16 elems: multiple of 8 (16B-aligned ds_read_b128 rows),
// 112 B = 28 words mod 32 -> lane pattern is <=2-way bank aliasing (free).
#define SROW 56
#define SROWS 48                  // staged rows: 42 real (r0-5 .. r0+36) + 6 pad
#define TROWS 32                  // tbuf: [col 0..31][row 0..47]

typedef __attribute__((ext_vector_type(8))) short short8;
typedef __attribute__((ext_vector_type(4))) float float4v;

// Gaussian window (sigma=1.5, ws=11), normalized (double-derived literals).
#define GW0 0.00102838f
#define GW1 0.00759877f
#define GW2 0.03600077f
#define GW3 0.10936069f
#define GW4 0.21300539f
#define GW5 0.26601172f

__device__ __forceinline__ unsigned short f2bf(float f) {
    unsigned u = __builtin_bit_cast(unsigned, f);
    u += 0x7FFF + ((u >> 16) & 1);            // round-to-nearest-even
    return (unsigned short)(u >> 16);
}
__device__ __forceinline__ unsigned pk2(float a, float b) {
    return (unsigned)f2bf(a) | ((unsigned)f2bf(b) << 16);
}

__global__ __launch_bounds__(256)
void ssim_tile_kernel(const float* __restrict__ xg, const float* __restrict__ yg,
                      float* __restrict__ partials) {
    // ch: 0=x 1=y 2=xx 3=yy 4=xy
    __shared__ unsigned short sbuf[5][SROWS][SROW];  // 26880 B, [row][col], col 0 = global c0-6
    __shared__ unsigned short tbuf[5][TROWS][SROW];  // 17920 B, [col][row] (transposed h-result)
    __shared__ float red[8];

    const float GW[11] = {GW0, GW1, GW2, GW3, GW4, GW5, GW4, GW3, GW2, GW1, GW0};

    const int tid  = threadIdx.x;
    const int lane = tid & 63;
    const int w    = tid >> 6;        // wave 0..3
    const int q    = lane >> 4;       // quad 0..3
    const int n16  = lane & 15;

    const int img = blockIdx.z;
    const int r00 = blockIdx.y * TS - 5;   // global row of local row 0
    const int c00 = blockIdx.x * TS - 6;   // global col of local col 0 (even -> float2 aligned)
    const float* __restrict__ xi = xg + (size_t)img * (IMG * IMG);
    const float* __restrict__ yi = yg + (size_t)img * (IMG * IMG);

    // ---- B fragments (Toeplitz Gaussian band), built once per lane ----
    // h-conv: out col n uses in local col n+1+t (t=0..10)  -> Bh[k][n] = g[k-n-1]
    // v-conv: out row t uses hres local row t+t' (t'=0..10) -> Bv[k][n] = g[k-n]
    short8 bh, bv;
    #pragma unroll
    for (int j = 0; j < 8; ++j) {
        int k = q * 8 + j;
        int ih = k - n16 - 1, iv = k - n16;
        float vh = 0.f, vv = 0.f;
        #pragma unroll
        for (int t = 0; t < 11; ++t) {
            if (ih == t) vh = GW[t];
            if (iv == t) vv = GW[t];
        }
        bh[j] = (short)f2bf(vh);
        bv[j] = (short)f2bf(vv);
    }

    // ---- Stage 48x48 (pairs of cols), compute 5 bf16 channels + L1 ----
    float l1_loc = 0.f;
    for (int idx = tid; idx < 48 * 24; idx += 256) {
        int pr = idx / 24;
        int pc = (idx - pr * 24) * 2;        // even col pair: never straddles image edge
        int gr = r00 + pr, gc = c00 + pc;
        float2 xv = make_float2(0.f, 0.f), yv = make_float2(0.f, 0.f);
        if ((unsigned)gr < 512u && (unsigned)gc < 512u) {
            xv = *(const float2*)(xi + (size_t)gr * IMG + gc);
            yv = *(const float2*)(yi + (size_t)gr * IMG + gc);
        }
        *(unsigned*)&sbuf[0][pr][pc] = pk2(xv.x, xv.y);
        *(unsigned*)&sbuf[1][pr][pc] = pk2(yv.x, yv.y);
        *(unsigned*)&sbuf[2][pr][pc] = pk2(xv.x * xv.x, xv.y * xv.y);
        *(unsigned*)&sbuf[3][pr][pc] = pk2(yv.x * yv.x, yv.y * yv.y);
        *(unsigned*)&sbuf[4][pr][pc] = pk2(xv.x * yv.x, xv.y * yv.y);
        // interior pixels of this tile: local rows 5..36, cols 6..37 (pairs 6..36)
        if (pr >= 5 && pr <= 36 && pc >= 6 && pc <= 36)
            l1_loc += fabsf(xv.x - yv.x) + fabsf(xv.y - yv.y);
    }
    __syncthreads();

    // ---- H-conv via MFMA: 5ch x 3 rowgroups x 2 colgroups = 30 units ----
    // A[m][k] = sbuf[ch][rg*16+m][cg*16+k]; D[m][n] = hres[row rg*16+m][outcol cg*16+n]
    // C/D: lane holds rows q*4+reg (reg 0..3), col n16 -> write transposed (4 consecutive rows)
    for (int u = w; u < 30; u += 4) {
        int ch = u / 6, rem = u - ch * 6;
        int rg = rem >> 1, cg = rem & 1;
        short8 a = *(const short8*)&sbuf[ch][rg * 16 + n16][cg * 16 + q * 8];
        float4v d = __builtin_amdgcn_mfma_f32_16x16x32_bf16(
            a, bh, (float4v){0.f, 0.f, 0.f, 0.f}, 0, 0, 0);
        unsigned lo = pk2(d[0], d[1]);
        unsigned hi = pk2(d[2], d[3]);
        *(uint2*)&tbuf[ch][cg * 16 + n16][rg * 16 + q * 4] = make_uint2(lo, hi);
    }
    __syncthreads();

    // ---- V-conv via MFMA: wave w owns quadrant (rg', cg'), all 5 channels ----
    // A[m][k] = tbuf[ch][cg'*16+m][rg'*16+k]  (m = out col offset, k = hres row)
    // D[m][n]: lane holds out row rg'*16+n16, out cols cg'*16 + q*4 + reg
    const int rgp = w >> 1, cgp = w & 1;
    float4v acc5[5];
    #pragma unroll
    for (int ch = 0; ch < 5; ++ch) {
        short8 a = *(const short8*)&tbuf[ch][cgp * 16 + n16][rgp * 16 + q * 8];
        acc5[ch] = __builtin_amdgcn_mfma_f32_16x16x32_bf16(
            a, bv, (float4v){0.f, 0.f, 0.f, 0.f}, 0, 0, 0);
    }

    // ---- Per-pixel SSIM (4 pixels per lane) ----
    float ssim_loc = 0.f;
    #pragma unroll
    for (int r = 0; r < 4; ++r) {
        float mu1 = acc5[0][r], mu2 = acc5[1][r];
        float e11 = acc5[2][r], e22 = acc5[3][r], e12 = acc5[4][r];
        float m1s = mu1 * mu1, m2s = mu2 * mu2, m12 = mu1 * mu2;
        float v1 = e11 - m1s, v2 = e22 - m2s, v12 = e12 - m12;
        float num = (2.f * m12 + C1F) * (2.f * v12 + C2F);
        float den = (m1s + m2s + C1F) * (v1 + v2 + C2F);
        ssim_loc += num / den;
    }

    // ---- Block reduction ----
    #pragma unroll
    for (int off = 32; off > 0; off >>= 1) {
        ssim_loc += __shfl_down(ssim_loc, off);
        l1_loc   += __shfl_down(l1_loc, off);
    }
    if (lane == 0) {
        red[w] = ssim_loc;
        red[4 + w] = l1_loc;
    }
    __syncthreads();
    if (tid == 0) {
        float ss = red[0] + red[1] + red[2] + red[3];
        float ll = red[4] + red[5] + red[6] + red[7];
        int bid = blockIdx.x + NT * (blockIdx.y + NT * blockIdx.z);
        partials[bid] = ss;
        partials[NBLOCKS + bid] = ll;
    }
}

__global__ __launch_bounds__(1024)
void finalize_kernel(const float* __restrict__ partials, float* __restrict__ out) {
    __shared__ double rs[16], rl[16];
    const int tid = threadIdx.x;
    double ss = 0.0, ll = 0.0;
    for (int i = tid; i < NBLOCKS; i += 1024) {
        ss += (double)partials[i];
        ll += (double)partials[NBLOCKS + i];
    }
    #pragma unroll
    for (int off = 32; off > 0; off >>= 1) {
        ss += __shfl_down(ss, off);
        ll += __shfl_down(ll, off);
    }
    int wave = tid >> 6, lane = tid & 63;
    if (lane == 0) { rs[wave] = ss; rl[wave] = ll; }
    __syncthreads();
    if (tid == 0) {
        double sst = 0.0, llt = 0.0;
        #pragma unroll
        for (int w = 0; w < 16; ++w) { sst += rs[w]; llt += rl[w]; }
        double invn = 1.0 / (double)NPIX;
        out[0] = (float)(llt * invn + (1.0 - sst * invn));
    }
}

extern "C" void kernel_launch(void* const* d_in, const int* in_sizes, int n_in,
                              void* d_out, int out_size, void* d_ws, size_t ws_size,
                              hipStream_t stream) {
    const float* x = (const float*)d_in[0];   // outputs
    const float* y = (const float*)d_in[1];   // labels
    float* out = (float*)d_out;
    float* partials = (float*)d_ws;           // 2*NBLOCKS*4 = 98,304 B

    dim3 grid(NT, NT, NIMG);
    ssim_tile_kernel<<<grid, dim3(256), 0, stream>>>(x, y, partials);
    finalize_kernel<<<1, dim3(1024), 0, stream>>>(partials, out);
}

// Round 6
// 165.539 us; speedup vs baseline: 1.2427x; 1.2427x over previous
//
#include <hip/hip_runtime.h>
#include <hip/hip_bf16.h>
#include <math.h>

#define IMG 512
#define TS 32                     // output tile 32x32
#define NT 16                     // tiles per side
#define NIMG 48                   // 16*3
#define NBLOCKS (NT * NT * NIMG)  // 12288
#define NPIX (16LL * 3 * 512 * 512)

#define C1F 0.0001f
#define C2F 0.0009f

// LDS row stride in bf16 elems: 56*2=112 B (16B-aligned rows for ds_read_b128;
// 28 words mod 32 -> <=2-way bank aliasing, free).
#define SROW 56
#define SROWS 48                  // 42 real rows (r0-5..r0+36) + 6 zero rows
#define TCOLS 32

typedef __attribute__((ext_vector_type(8))) short short8;
typedef __attribute__((ext_vector_type(4))) float float4v;

// Gaussian window (sigma=1.5, ws=11), normalized (double-derived literals).
#define GW0 0.00102838f
#define GW1 0.00759877f
#define GW2 0.03600077f
#define GW3 0.10936069f
#define GW4 0.21300539f
#define GW5 0.26601172f

__device__ __forceinline__ unsigned short f2bf(float f) {
    unsigned u = __builtin_bit_cast(unsigned, f);
    u += 0x7FFF + ((u >> 16) & 1);            // RNE
    return (unsigned short)(u >> 16);
}
// HW packed f32->bf16 (v_cvt_pk_bf16_f32) via HIP API; memcpy because
// __hip_bfloat162 is not trivially copyable (bit_cast rejected).
__device__ __forceinline__ unsigned pk2(float a, float b) {
    __hip_bfloat162 h = __float22bfloat162_rn(make_float2(a, b));
    unsigned u;
    __builtin_memcpy(&u, &h, 4);
    return u;
}

__global__ __launch_bounds__(256, 5)
void ssim_tile_kernel(const float* __restrict__ xg, const float* __restrict__ yg,
                      float* __restrict__ partials) {
    __shared__ unsigned short sbuf[2][SROWS][SROW];   // 10752 B  (x, y bf16)
    __shared__ unsigned short tbuf[5][TCOLS][SROW];   // 17920 B  (h-result, transposed)
    __shared__ float red[8];                          // total ~28.7 KB -> 5 blocks/CU

    const float GW[11] = {GW0, GW1, GW2, GW3, GW4, GW5, GW4, GW3, GW2, GW1, GW0};

    const int tid  = threadIdx.x;
    const int lane = tid & 63;
    const int w    = tid >> 6;        // wave 0..3
    const int q    = lane >> 4;       // quad 0..3
    const int n16  = lane & 15;

    const int img = blockIdx.z;
    const int r00 = blockIdx.y * TS - 5;   // global row of local row 0
    const int c00 = blockIdx.x * TS - 6;   // global col of local col 0 (even)
    const float* __restrict__ xi = xg + (size_t)img * (IMG * IMG);
    const float* __restrict__ yi = yg + (size_t)img * (IMG * IMG);

    // ---- B fragments (Toeplitz Gaussian band) ----
    // h-conv: out col n uses local in col n+1+t (t=0..10) -> Bh[k][n] = g[k-n-1]
    // v-conv: out row n uses hres local row n+t          -> Bv[k][n] = g[k-n]
    short8 bh, bv;
    #pragma unroll
    for (int j = 0; j < 8; ++j) {
        int k = q * 8 + j;
        int ih = k - n16 - 1, iv = k - n16;
        float vh = 0.f, vv = 0.f;
        #pragma unroll
        for (int t = 0; t < 11; ++t) {
            if (ih == t) vh = GW[t];
            if (iv == t) vv = GW[t];
        }
        bh[j] = (short)f2bf(vh);
        bv[j] = (short)f2bf(vv);
    }

    // ---- Stage x,y (bf16) + L1; rows 42..47 forced zero (no fetch, no NaN) ----
    float l1_loc = 0.f;
    for (int idx = tid; idx < SROWS * 24; idx += 256) {
        int pr = idx / 24;
        int pc = (idx - pr * 24) * 2;        // even col pair, never straddles edge
        int gr = r00 + pr, gc = c00 + pc;
        float2 xv = make_float2(0.f, 0.f), yv = make_float2(0.f, 0.f);
        if (pr < 42 && (unsigned)gr < 512u && (unsigned)gc < 512u) {
            xv = *(const float2*)(xi + (size_t)gr * IMG + gc);
            yv = *(const float2*)(yi + (size_t)gr * IMG + gc);
        }
        *(unsigned*)&sbuf[0][pr][pc] = pk2(xv.x, xv.y);
        *(unsigned*)&sbuf[1][pr][pc] = pk2(yv.x, yv.y);
        // interior pixels of this tile: local rows 5..36, col pairs 6..36
        if (pr >= 5 && pr <= 36 && pc >= 6 && pc <= 36)
            l1_loc += fabsf(xv.x - yv.x) + fabsf(xv.y - yv.y);
    }
    __syncthreads();

    // ---- H-conv via MFMA: 3 rowgroups x 2 colgroups = 6 units; xx/yy/xy
    //      fragments built in-register from the x,y fragments ----
    for (int u = w; u < 6; u += 4) {
        int rg = u >> 1, cg = u & 1;
        short8 ax = *(const short8*)&sbuf[0][rg * 16 + n16][cg * 16 + q * 8];
        short8 ay = *(const short8*)&sbuf[1][rg * 16 + n16][cg * 16 + q * 8];
        short8 axx, ayy, axy;
        {
            unsigned* px = (unsigned*)&ax;
            unsigned* py = (unsigned*)&ay;
            unsigned* pxx = (unsigned*)&axx;
            unsigned* pyy = (unsigned*)&ayy;
            unsigned* pxy = (unsigned*)&axy;
            #pragma unroll
            for (int r = 0; r < 4; ++r) {
                unsigned rx = px[r], ry = py[r];
                float xlo = __builtin_bit_cast(float, rx << 16);
                float xhi = __builtin_bit_cast(float, rx & 0xFFFF0000u);
                float ylo = __builtin_bit_cast(float, ry << 16);
                float yhi = __builtin_bit_cast(float, ry & 0xFFFF0000u);
                pxx[r] = pk2(xlo * xlo, xhi * xhi);
                pyy[r] = pk2(ylo * ylo, yhi * yhi);
                pxy[r] = pk2(xlo * ylo, xhi * yhi);
            }
        }
        // D: lane holds rows q*4+reg, out col n16 -> write transposed
        float4v d;
        d = __builtin_amdgcn_mfma_f32_16x16x32_bf16(ax, bh, (float4v){0.f,0.f,0.f,0.f}, 0, 0, 0);
        *(uint2*)&tbuf[0][cg * 16 + n16][rg * 16 + q * 4] = make_uint2(pk2(d[0], d[1]), pk2(d[2], d[3]));
        d = __builtin_amdgcn_mfma_f32_16x16x32_bf16(ay, bh, (float4v){0.f,0.f,0.f,0.f}, 0, 0, 0);
        *(uint2*)&tbuf[1][cg * 16 + n16][rg * 16 + q * 4] = make_uint2(pk2(d[0], d[1]), pk2(d[2], d[3]));
        d = __builtin_amdgcn_mfma_f32_16x16x32_bf16(axx, bh, (float4v){0.f,0.f,0.f,0.f}, 0, 0, 0);
        *(uint2*)&tbuf[2][cg * 16 + n16][rg * 16 + q * 4] = make_uint2(pk2(d[0], d[1]), pk2(d[2], d[3]));
        d = __builtin_amdgcn_mfma_f32_16x16x32_bf16(ayy, bh, (float4v){0.f,0.f,0.f,0.f}, 0, 0, 0);
        *(uint2*)&tbuf[3][cg * 16 + n16][rg * 16 + q * 4] = make_uint2(pk2(d[0], d[1]), pk2(d[2], d[3]));
        d = __builtin_amdgcn_mfma_f32_16x16x32_bf16(axy, bh, (float4v){0.f,0.f,0.f,0.f}, 0, 0, 0);
        *(uint2*)&tbuf[4][cg * 16 + n16][rg * 16 + q * 4] = make_uint2(pk2(d[0], d[1]), pk2(d[2], d[3]));
    }
    __syncthreads();

    // ---- V-conv via MFMA: wave w = quadrant (rg', cg'), 5 channels ----
    const int rgp = w >> 1, cgp = w & 1;
    float4v acc5[5];
    #pragma unroll
    for (int ch = 0; ch < 5; ++ch) {
        short8 a = *(const short8*)&tbuf[ch][cgp * 16 + n16][rgp * 16 + q * 8];
        acc5[ch] = __builtin_amdgcn_mfma_f32_16x16x32_bf16(
            a, bv, (float4v){0.f, 0.f, 0.f, 0.f}, 0, 0, 0);
    }

    // ---- Per-pixel SSIM (4 px/lane) ----
    float ssim_loc = 0.f;
    #pragma unroll
    for (int r = 0; r < 4; ++r) {
        float mu1 = acc5[0][r], mu2 = acc5[1][r];
        float e11 = acc5[2][r], e22 = acc5[3][r], e12 = acc5[4][r];
        float m1s = mu1 * mu1, m2s = mu2 * mu2, m12 = mu1 * mu2;
        float v1 = e11 - m1s, v2 = e22 - m2s, v12 = e12 - m12;
        float num = (2.f * m12 + C1F) * (2.f * v12 + C2F);
        float den = (m1s + m2s + C1F) * (v1 + v2 + C2F);
        ssim_loc += num / den;
    }

    // ---- Block reduction ----
    #pragma unroll
    for (int off = 32; off > 0; off >>= 1) {
        ssim_loc += __shfl_down(ssim_loc, off);
        l1_loc   += __shfl_down(l1_loc, off);
    }
    if (lane == 0) {
        red[w] = ssim_loc;
        red[4 + w] = l1_loc;
    }
    __syncthreads();
    if (tid == 0) {
        float ss = red[0] + red[1] + red[2] + red[3];
        float ll = red[4] + red[5] + red[6] + red[7];
        int bid = blockIdx.x + NT * (blockIdx.y + NT * blockIdx.z);
        partials[bid] = ss;
        partials[NBLOCKS + bid] = ll;
    }
}

__global__ __launch_bounds__(1024)
void finalize_kernel(const float* __restrict__ partials, float* __restrict__ out) {
    __shared__ double rs[16], rl[16];
    const int tid = threadIdx.x;
    double ss = 0.0, ll = 0.0;
    for (int i = tid; i < NBLOCKS; i += 1024) {
        ss += (double)partials[i];
        ll += (double)partials[NBLOCKS + i];
    }
    #pragma unroll
    for (int off = 32; off > 0; off >>= 1) {
        ss += __shfl_down(ss, off);
        ll += __shfl_down(ll, off);
    }
    int wave = tid >> 6, lane = tid & 63;
    if (lane == 0) { rs[wave] = ss; rl[wave] = ll; }
    __syncthreads();
    if (tid == 0) {
        double sst = 0.0, llt = 0.0;
        #pragma unroll
        for (int w = 0; w < 16; ++w) { sst += rs[w]; llt += rl[w]; }
        double invn = 1.0 / (double)NPIX;
        out[0] = (float)(llt * invn + (1.0 - sst * invn));
    }
}

extern "C" void kernel_launch(void* const* d_in, const int* in_sizes, int n_in,
                              void* d_out, int out_size, void* d_ws, size_t ws_size,
                              hipStream_t stream) {
    const float* x = (const float*)d_in[0];   // outputs
    const float* y = (const float*)d_in[1];   // labels
    float* out = (float*)d_out;
    float* partials = (float*)d_ws;           // 2*NBLOCKS*4 = 98,304 B

    dim3 grid(NT, NT, NIMG);
    ssim_tile_kernel<<<grid, dim3(256), 0, stream>>>(x, y, partials);
    finalize_kernel<<<1, dim3(1024), 0, stream>>>(partials, out);
}

// Round 7
// 162.035 us; speedup vs baseline: 1.2696x; 1.0216x over previous
//
#include <hip/hip_runtime.h>
#include <hip/hip_bf16.h>
#include <math.h>

#define IMG 512
#define TS 32                     // output tile 32x32
#define NT 16                     // tiles per side
#define NIMG 48                   // 16*3
#define NBLOCKS (NT * NT * NIMG)  // 12288
#define NPIX (16LL * 3 * 512 * 512)

#define C1F 0.0001f
#define C2F 0.0009f

// LDS row stride in bf16 elems: 56*2=112 B (16B-aligned rows; 28 words mod 32
// -> <=2-way bank aliasing, free).
#define SROW 56
#define SROWS 48                  // 42 real rows (r0-5..r0+36) + 6 zero rows
#define TCOLS 32

typedef __attribute__((ext_vector_type(8))) short short8;
typedef __attribute__((ext_vector_type(4))) float float4v;

// Gaussian window (sigma=1.5, ws=11), normalized (double-derived literals).
#define GW0 0.00102838f
#define GW1 0.00759877f
#define GW2 0.03600077f
#define GW3 0.10936069f
#define GW4 0.21300539f
#define GW5 0.26601172f

__device__ __forceinline__ unsigned short f2bf(float f) {
    unsigned u = __builtin_bit_cast(unsigned, f);
    u += 0x7FFF + ((u >> 16) & 1);            // RNE
    return (unsigned short)(u >> 16);
}
// HW packed f32->bf16 (v_cvt_pk_bf16_f32); memcpy because __hip_bfloat162
// is not trivially copyable.
__device__ __forceinline__ unsigned pk2(float a, float b) {
    __hip_bfloat162 h = __float22bfloat162_rn(make_float2(a, b));
    unsigned u;
    __builtin_memcpy(&u, &h, 4);
    return u;
}

__global__ __launch_bounds__(256, 5)
void ssim_tile_kernel(const float* __restrict__ xg, const float* __restrict__ yg,
                      float* __restrict__ partials) {
    __shared__ unsigned short sbuf[2][SROWS][SROW];   // 10752 B  (x, y bf16)
    __shared__ unsigned short tbuf[5][TCOLS][SROW];   // 17920 B  (h-result, transposed)
    __shared__ float red[8];                          // ~28.7 KB -> 5 blocks/CU

    const float GW[11] = {GW0, GW1, GW2, GW3, GW4, GW5, GW4, GW3, GW2, GW1, GW0};

    const int tid  = threadIdx.x;
    const int lane = tid & 63;
    const int w    = tid >> 6;        // wave 0..3
    const int q    = lane >> 4;       // quad 0..3
    const int n16  = lane & 15;

    const int img = blockIdx.z;
    const int r00  = blockIdx.y * TS - 5;   // global row of staged row 0
    const int c00a = blockIdx.x * TS - 8;   // global col of staged col 0 (16B-aligned)
    const float* __restrict__ xi = xg + (size_t)img * (IMG * IMG);
    const float* __restrict__ yi = yg + (size_t)img * (IMG * IMG);

    // ---- B fragments (Toeplitz Gaussian band) ----
    // h-conv: out col n reads staged col n+3+t (t=0..10) -> Bh[k][n] = g[k-n-3]
    // v-conv: out row n reads hres row n+t               -> Bv[k][n] = g[k-n]
    short8 bh, bv;
    #pragma unroll
    for (int j = 0; j < 8; ++j) {
        int k = q * 8 + j;
        int ih = k - n16 - 3, iv = k - n16;
        float vh = 0.f, vv = 0.f;
        #pragma unroll
        for (int t = 0; t < 11; ++t) {
            if (ih == t) vh = GW[t];
            if (iv == t) vv = GW[t];
        }
        bh[j] = (short)f2bf(vh);
        bv[j] = (short)f2bf(vv);
    }

    // ---- Stage x,y as bf16, float4 granularity (48 rows x 12 float4) ----
    // OOB is always whole-float4 (image width 512 = 0 mod 4, base aligned),
    // so one predicated path serves interior and edge blocks alike.
    for (int u = tid; u < 576; u += 256) {
        int pr  = u / 12;               // 0..47
        int pc4 = (u - pr * 12) << 2;   // 0,4,...,44
        int gr = r00 + pr, gc = c00a + pc4;
        float4 xv = make_float4(0.f, 0.f, 0.f, 0.f);
        float4 yv = make_float4(0.f, 0.f, 0.f, 0.f);
        if (pr < 42 && (unsigned)gr < 512u && (unsigned)gc < 512u) {
            size_t o = (size_t)gr * IMG + gc;
            xv = *(const float4*)(xi + o);
            yv = *(const float4*)(yi + o);
        }
        *(uint2*)&sbuf[0][pr][pc4] = make_uint2(pk2(xv.x, xv.y), pk2(xv.z, xv.w));
        *(uint2*)&sbuf[1][pr][pc4] = make_uint2(pk2(yv.x, yv.y), pk2(yv.z, yv.w));
    }

    // ---- L1 over this tile's 32x32 interior: exactly 256 float4-pairs,
    //      aligned, never OOB, L1/L2-hot (same lines staged above) ----
    float l1_loc;
    {
        int r  = tid >> 3;
        int c4 = (tid & 7) << 2;
        size_t o = (size_t)(blockIdx.y * TS + r) * IMG + blockIdx.x * TS + c4;
        float4 a = *(const float4*)(xi + o);
        float4 b = *(const float4*)(yi + o);
        l1_loc = fabsf(a.x - b.x) + fabsf(a.y - b.y) + fabsf(a.z - b.z) + fabsf(a.w - b.w);
    }
    __syncthreads();

    // ---- H-conv via MFMA: 3 rowgroups x 2 colgroups = 6 units; xx/yy/xy
    //      fragments built in-register from x,y fragments ----
    for (int u = w; u < 6; u += 4) {
        int rg = u >> 1, cg = u & 1;
        short8 ax = *(const short8*)&sbuf[0][rg * 16 + n16][cg * 16 + q * 8];
        short8 ay = *(const short8*)&sbuf[1][rg * 16 + n16][cg * 16 + q * 8];
        short8 axx, ayy, axy;
        {
            unsigned* px = (unsigned*)&ax;
            unsigned* py = (unsigned*)&ay;
            unsigned* pxx = (unsigned*)&axx;
            unsigned* pyy = (unsigned*)&ayy;
            unsigned* pxy = (unsigned*)&axy;
            #pragma unroll
            for (int r = 0; r < 4; ++r) {
                unsigned rx = px[r], ry = py[r];
                float xlo = __builtin_bit_cast(float, rx << 16);
                float xhi = __builtin_bit_cast(float, rx & 0xFFFF0000u);
                float ylo = __builtin_bit_cast(float, ry << 16);
                float yhi = __builtin_bit_cast(float, ry & 0xFFFF0000u);
                pxx[r] = pk2(xlo * xlo, xhi * xhi);
                pyy[r] = pk2(ylo * ylo, yhi * yhi);
                pxy[r] = pk2(xlo * ylo, xhi * yhi);
            }
        }
        // D: lane holds rows q*4+reg, out col n16 -> write transposed
        float4v d;
        d = __builtin_amdgcn_mfma_f32_16x16x32_bf16(ax, bh, (float4v){0.f,0.f,0.f,0.f}, 0, 0, 0);
        *(uint2*)&tbuf[0][cg * 16 + n16][rg * 16 + q * 4] = make_uint2(pk2(d[0], d[1]), pk2(d[2], d[3]));
        d = __builtin_amdgcn_mfma_f32_16x16x32_bf16(ay, bh, (float4v){0.f,0.f,0.f,0.f}, 0, 0, 0);
        *(uint2*)&tbuf[1][cg * 16 + n16][rg * 16 + q * 4] = make_uint2(pk2(d[0], d[1]), pk2(d[2], d[3]));
        d = __builtin_amdgcn_mfma_f32_16x16x32_bf16(axx, bh, (float4v){0.f,0.f,0.f,0.f}, 0, 0, 0);
        *(uint2*)&tbuf[2][cg * 16 + n16][rg * 16 + q * 4] = make_uint2(pk2(d[0], d[1]), pk2(d[2], d[3]));
        d = __builtin_amdgcn_mfma_f32_16x16x32_bf16(ayy, bh, (float4v){0.f,0.f,0.f,0.f}, 0, 0, 0);
        *(uint2*)&tbuf[3][cg * 16 + n16][rg * 16 + q * 4] = make_uint2(pk2(d[0], d[1]), pk2(d[2], d[3]));
        d = __builtin_amdgcn_mfma_f32_16x16x32_bf16(axy, bh, (float4v){0.f,0.f,0.f,0.f}, 0, 0, 0);
        *(uint2*)&tbuf[4][cg * 16 + n16][rg * 16 + q * 4] = make_uint2(pk2(d[0], d[1]), pk2(d[2], d[3]));
    }
    __syncthreads();

    // ---- V-conv via MFMA: wave w = quadrant (rg', cg'), 5 channels ----
    const int rgp = w >> 1, cgp = w & 1;
    float4v acc5[5];
    #pragma unroll
    for (int ch = 0; ch < 5; ++ch) {
        short8 a = *(const short8*)&tbuf[ch][cgp * 16 + n16][rgp * 16 + q * 8];
        acc5[ch] = __builtin_amdgcn_mfma_f32_16x16x32_bf16(
            a, bv, (float4v){0.f, 0.f, 0.f, 0.f}, 0, 0, 0);
    }

    // ---- Per-pixel SSIM (4 px/lane); rcp instead of div (1-ulp, 3.4x headroom) ----
    float ssim_loc = 0.f;
    #pragma unroll
    for (int r = 0; r < 4; ++r) {
        float mu1 = acc5[0][r], mu2 = acc5[1][r];
        float e11 = acc5[2][r], e22 = acc5[3][r], e12 = acc5[4][r];
        float m1s = mu1 * mu1, m2s = mu2 * mu2, m12 = mu1 * mu2;
        float v1 = e11 - m1s, v2 = e22 - m2s, v12 = e12 - m12;
        float num = (2.f * m12 + C1F) * (2.f * v12 + C2F);
        float den = (m1s + m2s + C1F) * (v1 + v2 + C2F);
        ssim_loc = fmaf(num, __builtin_amdgcn_rcpf(den), ssim_loc);
    }

    // ---- Block reduction ----
    #pragma unroll
    for (int off = 32; off > 0; off >>= 1) {
        ssim_loc += __shfl_down(ssim_loc, off);
        l1_loc   += __shfl_down(l1_loc, off);
    }
    if (lane == 0) {
        red[w] = ssim_loc;
        red[4 + w] = l1_loc;
    }
    __syncthreads();
    if (tid == 0) {
        float ss = red[0] + red[1] + red[2] + red[3];
        float ll = red[4] + red[5] + red[6] + red[7];
        int bid = blockIdx.x + NT * (blockIdx.y + NT * blockIdx.z);
        partials[bid] = ss;
        partials[NBLOCKS + bid] = ll;
    }
}

__global__ __launch_bounds__(1024)
void finalize_kernel(const float* __restrict__ partials, float* __restrict__ out) {
    __shared__ double rs[16], rl[16];
    const int tid = threadIdx.x;
    double ss = 0.0, ll = 0.0;
    for (int i = tid; i < NBLOCKS; i += 1024) {
        ss += (double)partials[i];
        ll += (double)partials[NBLOCKS + i];
    }
    #pragma unroll
    for (int off = 32; off > 0; off >>= 1) {
        ss += __shfl_down(ss, off);
        ll += __shfl_down(ll, off);
    }
    int wave = tid >> 6, lane = tid & 63;
    if (lane == 0) { rs[wave] = ss; rl[wave] = ll; }
    __syncthreads();
    if (tid == 0) {
        double sst = 0.0, llt = 0.0;
        #pragma unroll
        for (int w = 0; w < 16; ++w) { sst += rs[w]; llt += rl[w]; }
        double invn = 1.0 / (double)NPIX;
        out[0] = (float)(llt * invn + (1.0 - sst * invn));
    }
}

extern "C" void kernel_launch(void* const* d_in, const int* in_sizes, int n_in,
                              void* d_out, int out_size, void* d_ws, size_t ws_size,
                              hipStream_t stream) {
    const float* x = (const float*)d_in[0];   // outputs
    const float* y = (const float*)d_in[1];   // labels
    float* out = (float*)d_out;
    float* partials = (float*)d_ws;           // 2*NBLOCKS*4 = 98,304 B

    dim3 grid(NT, NT, NIMG);
    ssim_tile_kernel<<<grid, dim3(256), 0, stream>>>(x, y, partials);
    finalize_kernel<<<1, dim3(1024), 0, stream>>>(partials, out);
}

// Round 8
// 153.956 us; speedup vs baseline: 1.3362x; 1.0525x over previous
//
#include <hip/hip_runtime.h>
#include <hip/hip_bf16.h>
#include <math.h>

#define IMG 512
#define TS 32                     // output tile 32x32
#define NT 16                     // tiles per side
#define NIMG 48                   // 16*3
#define NBLOCKS (NT * NT * NIMG)  // 12288
#define NPIX (16LL * 3 * 512 * 512)

#define C1F 0.0001f
#define C2F 0.0009f

// LDS row stride in bf16 elems: 56*2=112 B (16B-aligned rows; 28 words mod 32
// -> <=2-way bank aliasing, free).
#define SROW 56
#define SROWS 48                  // 42 real rows (r0-5..r0+36) + 6 zero rows
#define TCOLS 32

typedef __attribute__((ext_vector_type(8))) short short8;
typedef __attribute__((ext_vector_type(4))) float float4v;

// Gaussian window (sigma=1.5, ws=11), normalized (double-derived literals).
#define GW0 0.00102838f
#define GW1 0.00759877f
#define GW2 0.03600077f
#define GW3 0.10936069f
#define GW4 0.21300539f
#define GW5 0.26601172f

__device__ __forceinline__ unsigned short f2bf(float f) {
    unsigned u = __builtin_bit_cast(unsigned, f);
    u += 0x7FFF + ((u >> 16) & 1);            // RNE
    return (unsigned short)(u >> 16);
}
// HW packed f32->bf16 (v_cvt_pk_bf16_f32); memcpy because __hip_bfloat162
// is not trivially copyable.
__device__ __forceinline__ unsigned pk2(float a, float b) {
    __hip_bfloat162 h = __float22bfloat162_rn(make_float2(a, b));
    unsigned u;
    __builtin_memcpy(&u, &h, 4);
    return u;
}

__global__ __launch_bounds__(256, 5)
void ssim_tile_kernel(const float* __restrict__ xg, const float* __restrict__ yg,
                      float* __restrict__ partials) {
    __shared__ unsigned short sbuf[2][SROWS][SROW];   // 10752 B  (x, y bf16)
    __shared__ unsigned short tbuf[5][TCOLS][SROW];   // 17920 B  (h-result, transposed)
    __shared__ unsigned short gwtbl[16];              // bf16 Gaussian taps, [11..15]=0
    __shared__ float red[8];                          // ~28.7 KB -> 5 blocks/CU

    const int tid  = threadIdx.x;
    const int lane = tid & 63;
    const int w    = tid >> 6;        // wave 0..3
    const int q    = lane >> 4;       // quad 0..3
    const int n16  = lane & 15;

    const int img = blockIdx.z;
    const int r00  = blockIdx.y * TS - 5;   // global row of staged row 0
    const int c00a = blockIdx.x * TS - 8;   // global col of staged col 0 (16B-aligned)
    const float* __restrict__ xi = xg + (size_t)img * (IMG * IMG);
    const float* __restrict__ yi = yg + (size_t)img * (IMG * IMG);

    // ---- Fill bf16 Gaussian tap table (constants folded at compile time) ----
    if (tid < 16) {
        const float gwf[11] = {GW0, GW1, GW2, GW3, GW4, GW5, GW4, GW3, GW2, GW1, GW0};
        unsigned short v = 0;
        #pragma unroll
        for (int t = 0; t < 11; ++t)
            if (tid == t) v = f2bf(gwf[t]);
        gwtbl[tid] = v;
    }

    // ---- Stage x,y as bf16, float4 granularity (48 rows x 12 float4) ----
    // OOB is always whole-float4 (image width 512 = 0 mod 4, base aligned),
    // so one predicated path serves interior and edge blocks alike.
    for (int u = tid; u < 576; u += 256) {
        int pr  = u / 12;               // 0..47
        int pc4 = (u - pr * 12) << 2;   // 0,4,...,44
        int gr = r00 + pr, gc = c00a + pc4;
        float4 xv = make_float4(0.f, 0.f, 0.f, 0.f);
        float4 yv = make_float4(0.f, 0.f, 0.f, 0.f);
        if (pr < 42 && (unsigned)gr < 512u && (unsigned)gc < 512u) {
            size_t o = (size_t)gr * IMG + gc;
            xv = *(const float4*)(xi + o);
            yv = *(const float4*)(yi + o);
        }
        *(uint2*)&sbuf[0][pr][pc4] = make_uint2(pk2(xv.x, xv.y), pk2(xv.z, xv.w));
        *(uint2*)&sbuf[1][pr][pc4] = make_uint2(pk2(yv.x, yv.y), pk2(yv.z, yv.w));
    }

    // ---- L1 over this tile's 32x32 interior: 256 float4-pairs, aligned,
    //      never OOB, L1/L2-hot (same lines staged above) ----
    float l1_loc;
    {
        int r  = tid >> 3;
        int c4 = (tid & 7) << 2;
        size_t o = (size_t)(blockIdx.y * TS + r) * IMG + blockIdx.x * TS + c4;
        float4 a = *(const float4*)(xi + o);
        float4 b = *(const float4*)(yi + o);
        l1_loc = fabsf(a.x - b.x) + fabsf(a.y - b.y) + fabsf(a.z - b.z) + fabsf(a.w - b.w);
    }
    __syncthreads();

    // ---- B fragments from LDS table (min-trick: OOB index -> >=11 -> 0) ----
    // h-conv: out col n reads staged col n+3+t -> Bh[k][n] = g[k-n-3]
    // v-conv: out row n reads hres row n+t     -> Bv[k][n] = g[k-n]
    short8 bh, bv;
    {
        int baseh = q * 8 - n16 - 3;
        int basev = q * 8 - n16;
        #pragma unroll
        for (int j = 0; j < 8; ++j) {
            unsigned ih = min((unsigned)(baseh + j), 15u);
            unsigned iv = min((unsigned)(basev + j), 15u);
            bh[j] = (short)gwtbl[ih];
            bv[j] = (short)gwtbl[iv];
        }
    }

    // ---- H-conv via MFMA: 3 rowgroups x 2 colgroups = 6 units; xx/yy/xy
    //      fragments built in-register from x,y fragments ----
    for (int u = w; u < 6; u += 4) {
        int rg = u >> 1, cg = u & 1;
        short8 ax = *(const short8*)&sbuf[0][rg * 16 + n16][cg * 16 + q * 8];
        short8 ay = *(const short8*)&sbuf[1][rg * 16 + n16][cg * 16 + q * 8];
        short8 axx, ayy, axy;
        {
            unsigned* px = (unsigned*)&ax;
            unsigned* py = (unsigned*)&ay;
            unsigned* pxx = (unsigned*)&axx;
            unsigned* pyy = (unsigned*)&ayy;
            unsigned* pxy = (unsigned*)&axy;
            #pragma unroll
            for (int r = 0; r < 4; ++r) {
                unsigned rx = px[r], ry = py[r];
                float xlo = __builtin_bit_cast(float, rx << 16);
                float xhi = __builtin_bit_cast(float, rx & 0xFFFF0000u);
                float ylo = __builtin_bit_cast(float, ry << 16);
                float yhi = __builtin_bit_cast(float, ry & 0xFFFF0000u);
                pxx[r] = pk2(xlo * xlo, xhi * xhi);
                pyy[r] = pk2(ylo * ylo, yhi * yhi);
                pxy[r] = pk2(xlo * ylo, xhi * yhi);
            }
        }
        // D: lane holds rows q*4+reg, out col n16 -> write transposed
        float4v d;
        d = __builtin_amdgcn_mfma_f32_16x16x32_bf16(ax, bh, (float4v){0.f,0.f,0.f,0.f}, 0, 0, 0);
        *(uint2*)&tbuf[0][cg * 16 + n16][rg * 16 + q * 4] = make_uint2(pk2(d[0], d[1]), pk2(d[2], d[3]));
        d = __builtin_amdgcn_mfma_f32_16x16x32_bf16(ay, bh, (float4v){0.f,0.f,0.f,0.f}, 0, 0, 0);
        *(uint2*)&tbuf[1][cg * 16 + n16][rg * 16 + q * 4] = make_uint2(pk2(d[0], d[1]), pk2(d[2], d[3]));
        d = __builtin_amdgcn_mfma_f32_16x16x32_bf16(axx, bh, (float4v){0.f,0.f,0.f,0.f}, 0, 0, 0);
        *(uint2*)&tbuf[2][cg * 16 + n16][rg * 16 + q * 4] = make_uint2(pk2(d[0], d[1]), pk2(d[2], d[3]));
        d = __builtin_amdgcn_mfma_f32_16x16x32_bf16(ayy, bh, (float4v){0.f,0.f,0.f,0.f}, 0, 0, 0);
        *(uint2*)&tbuf[3][cg * 16 + n16][rg * 16 + q * 4] = make_uint2(pk2(d[0], d[1]), pk2(d[2], d[3]));
        d = __builtin_amdgcn_mfma_f32_16x16x32_bf16(axy, bh, (float4v){0.f,0.f,0.f,0.f}, 0, 0, 0);
        *(uint2*)&tbuf[4][cg * 16 + n16][rg * 16 + q * 4] = make_uint2(pk2(d[0], d[1]), pk2(d[2], d[3]));
    }
    __syncthreads();

    // ---- V-conv via MFMA: wave w = quadrant (rg', cg'), 5 channels ----
    const int rgp = w >> 1, cgp = w & 1;
    float4v acc5[5];
    #pragma unroll
    for (int ch = 0; ch < 5; ++ch) {
        short8 a = *(const short8*)&tbuf[ch][cgp * 16 + n16][rgp * 16 + q * 8];
        acc5[ch] = __builtin_amdgcn_mfma_f32_16x16x32_bf16(
            a, bv, (float4v){0.f, 0.f, 0.f, 0.f}, 0, 0, 0);
    }

    // ---- Per-pixel SSIM (4 px/lane); rcp (1-ulp, 3.4x error headroom) ----
    float ssim_loc = 0.f;
    #pragma unroll
    for (int r = 0; r < 4; ++r) {
        float mu1 = acc5[0][r], mu2 = acc5[1][r];
        float e11 = acc5[2][r], e22 = acc5[3][r], e12 = acc5[4][r];
        float m1s = mu1 * mu1, m2s = mu2 * mu2, m12 = mu1 * mu2;
        float v1 = e11 - m1s, v2 = e22 - m2s, v12 = e12 - m12;
        float num = (2.f * m12 + C1F) * (2.f * v12 + C2F);
        float den = (m1s + m2s + C1F) * (v1 + v2 + C2F);
        ssim_loc = fmaf(num, __builtin_amdgcn_rcpf(den), ssim_loc);
    }

    // ---- Block reduction ----
    #pragma unroll
    for (int off = 32; off > 0; off >>= 1) {
        ssim_loc += __shfl_down(ssim_loc, off);
        l1_loc   += __shfl_down(l1_loc, off);
    }
    if (lane == 0) {
        red[w] = ssim_loc;
        red[4 + w] = l1_loc;
    }
    __syncthreads();
    if (tid == 0) {
        float ss = red[0] + red[1] + red[2] + red[3];
        float ll = red[4] + red[5] + red[6] + red[7];
        int bid = blockIdx.x + NT * (blockIdx.y + NT * blockIdx.z);
        partials[bid] = ss;
        partials[NBLOCKS + bid] = ll;
    }
}

__global__ __launch_bounds__(1024)
void finalize_kernel(const float* __restrict__ partials, float* __restrict__ out) {
    __shared__ double rs[16], rl[16];
    const int tid = threadIdx.x;
    double ss = 0.0, ll = 0.0;
    for (int i = tid; i < NBLOCKS; i += 1024) {
        ss += (double)partials[i];
        ll += (double)partials[NBLOCKS + i];
    }
    #pragma unroll
    for (int off = 32; off > 0; off >>= 1) {
        ss += __shfl_down(ss, off);
        ll += __shfl_down(ll, off);
    }
    int wave = tid >> 6, lane = tid & 63;
    if (lane == 0) { rs[wave] = ss; rl[wave] = ll; }
    __syncthreads();
    if (tid == 0) {
        double sst = 0.0, llt = 0.0;
        #pragma unroll
        for (int w = 0; w < 16; ++w) { sst += rs[w]; llt += rl[w]; }
        double invn = 1.0 / (double)NPIX;
        out[0] = (float)(llt * invn + (1.0 - sst * invn));
    }
}

extern "C" void kernel_launch(void* const* d_in, const int* in_sizes, int n_in,
                              void* d_out, int out_size, void* d_ws, size_t ws_size,
                              hipStream_t stream) {
    const float* x = (const float*)d_in[0];   // outputs
    const float* y = (const float*)d_in[1];   // labels
    float* out = (float*)d_out;
    float* partials = (float*)d_ws;           // 2*NBLOCKS*4 = 98,304 B

    dim3 grid(NT, NT, NIMG);
    ssim_tile_kernel<<<grid, dim3(256), 0, stream>>>(x, y, partials);
    finalize_kernel<<<1, dim3(1024), 0, stream>>>(partials, out);
}